// Round 18
// baseline (355.716 us; speedup 1.0000x reference)
//
#include <hip/hip_runtime.h>
#include <hip/hip_fp8.h>
#include <math.h>

#define DD 128
#define CC 16
#define ALPHA_ 0.5f
#define EPS_LN 1e-5f
#define EPS_COS 1e-8f

typedef _Float16 h4 __attribute__((ext_vector_type(4)));
typedef _Float16 f16x8 __attribute__((ext_vector_type(8)));
typedef float f32x4 __attribute__((ext_vector_type(4)));
typedef long lx2 __attribute__((ext_vector_type(2)));

__device__ __forceinline__ unsigned pk_fp8x4(float v0, float v1, float v2, float v3) {
#if __has_builtin(__builtin_amdgcn_cvt_pk_fp8_f32)
    int u = 0;
    u = __builtin_amdgcn_cvt_pk_fp8_f32(v0, v1, u, false);
    u = __builtin_amdgcn_cvt_pk_fp8_f32(v2, v3, u, true);
    return (unsigned)u;
#else
    __hip_fp8_e4m3 a(v0), b(v1), c(v2), d(v3);
    return (unsigned)a.__x | ((unsigned)b.__x << 8)
         | ((unsigned)c.__x << 16) | ((unsigned)d.__x << 24);
#endif
}

// ============ FAT kernel: ft (MFMA transform) ∥ bpart (bucket partition) ====
__global__ __launch_bounds__(256, 2) void ft_bpart_kernel(
    const float* __restrict__ feat, const float* __restrict__ W,
    const float* __restrict__ bias, const float* __restrict__ gamma,
    const float* __restrict__ beta, unsigned* __restrict__ hn8, int N,
    const int* __restrict__ s0, const int* __restrict__ d0,
    const int* __restrict__ s1, const int* __restrict__ d1,
    const int* __restrict__ s2, const int* __restrict__ d2,
    int* __restrict__ gcur, unsigned* __restrict__ stage,
    int E, int NB, int cap, int FTB, int PB)
{
    __shared__ int cnt[512];
    __shared__ int rbase[512];

    if ((int)blockIdx.x >= FTB) {
        // ---------------- bpart ----------------
        const int bidx = blockIdx.x - FTB;
        const int tid = threadIdx.x;
        for (int i = tid; i < NB; i += 256) cnt[i] = 0;
        __syncthreads();
        const int tot = 3 * E;
        const int chunk = (tot + PB - 1) / PB;
        const int lo = bidx * chunk, hi = min(lo + chunk, tot);
        for (int i = lo + tid; i < hi; i += 256) {
            int src = (i < E) ? s0[i] : (i < 2 * E) ? s1[i - E] : s2[i - 2 * E];
            atomicAdd(&cnt[src >> 8], 1);
        }
        __syncthreads();
        for (int i = tid; i < NB; i += 256) {
            int c = cnt[i];
            rbase[i] = c ? (i * cap + atomicAdd(&gcur[i], c)) : 0;
            cnt[i] = 0;
        }
        __syncthreads();
        for (int i = lo + tid; i < hi; i += 256) {
            int src, dst, cls;
            if (i < E)          { src = s0[i];         dst = d0[i];         cls = 0; }
            else if (i < 2 * E) { src = s1[i - E];     dst = d1[i - E];     cls = 1; }
            else                { src = s2[i - 2 * E]; dst = d2[i - 2 * E]; cls = 2; }
            int b = src >> 8;
            int pos = rbase[b] + atomicAdd(&cnt[b], 1);
            stage[pos] = (unsigned)dst | ((unsigned)cls << 17)
                       | ((unsigned)(src & 255) << 19);
        }
        return;
    }

    // ---------------- ft (MFMA) ----------------
    const int lane = threadIdx.x & 63;
    const int c16  = lane & 15;
    const int g    = lane >> 4;
    const int wv   = ((int)blockIdx.x * 256 + (int)threadIdx.x) >> 6;
    const int nwv  = (FTB * 256) >> 6;

    f16x8 wf[8][4];
#pragma unroll
    for (int jt = 0; jt < 8; ++jt) {
        const float* wr = W + (size_t)(jt * 16 + c16) * 128 + g * 8;
#pragma unroll
        for (int s = 0; s < 4; ++s) {
            float4 lo = *(const float4*)(wr + s * 32);
            float4 hi = *(const float4*)(wr + s * 32 + 4);
            f16x8 f;
            f[0] = (_Float16)lo.x; f[1] = (_Float16)lo.y;
            f[2] = (_Float16)lo.z; f[3] = (_Float16)lo.w;
            f[4] = (_Float16)hi.x; f[5] = (_Float16)hi.y;
            f[6] = (_Float16)hi.z; f[7] = (_Float16)hi.w;
            wf[jt][s] = f;
        }
    }

    const int ntiles = (N + 15) >> 4;
    for (int t = wv; t < ntiles; t += nwv) {
        const int i = (t << 4) + c16;
        const float* fr = feat + (size_t)min(i, N - 1) * 128 + g * 8;
        f16x8 bf[4];
#pragma unroll
        for (int s = 0; s < 4; ++s) {
            float4 lo = *(const float4*)(fr + s * 32);
            float4 hi = *(const float4*)(fr + s * 32 + 4);
            f16x8 f;
            f[0] = (_Float16)lo.x; f[1] = (_Float16)lo.y;
            f[2] = (_Float16)lo.z; f[3] = (_Float16)lo.w;
            f[4] = (_Float16)hi.x; f[5] = (_Float16)hi.y;
            f[6] = (_Float16)hi.z; f[7] = (_Float16)hi.w;
            bf[s] = f;
        }

        f32x4 acc[8] = {};
#pragma unroll
        for (int s = 0; s < 4; ++s)
#pragma unroll
            for (int jt = 0; jt < 8; ++jt)
                acc[jt] = __builtin_amdgcn_mfma_f32_16x16x32_f16(
                    wf[jt][s], bf[s], acc[jt], 0, 0, 0);

        float s1 = 0.f, s2 = 0.f;
#pragma unroll
        for (int jt = 0; jt < 8; ++jt) {
            float4 bb = ((const float4*)bias)[jt * 4 + g];
            float h0 = acc[jt][0] + bb.x, h1 = acc[jt][1] + bb.y;
            float h2_ = acc[jt][2] + bb.z, h3 = acc[jt][3] + bb.w;
            acc[jt][0] = h0; acc[jt][1] = h1; acc[jt][2] = h2_; acc[jt][3] = h3;
            s1 += h0 + h1 + h2_ + h3;
            s2 += h0 * h0 + h1 * h1 + h2_ * h2_ + h3 * h3;
        }
        s1 += __shfl_xor(s1, 16); s1 += __shfl_xor(s1, 32);
        s2 += __shfl_xor(s2, 16); s2 += __shfl_xor(s2, 32);
        float mu   = s1 * (1.f / 128.f);
        float var  = s2 * (1.f / 128.f) - mu * mu;
        float rstd = rsqrtf(var + EPS_LN);

        float nsq = 0.f;
#pragma unroll
        for (int jt = 0; jt < 8; ++jt) {
            float4 gg = ((const float4*)gamma)[jt * 4 + g];
            float4 be = ((const float4*)beta)[jt * 4 + g];
            float v0 = fmaxf((acc[jt][0] - mu) * rstd * gg.x + be.x, 0.f);
            float v1 = fmaxf((acc[jt][1] - mu) * rstd * gg.y + be.y, 0.f);
            float v2 = fmaxf((acc[jt][2] - mu) * rstd * gg.z + be.z, 0.f);
            float v3 = fmaxf((acc[jt][3] - mu) * rstd * gg.w + be.w, 0.f);
            acc[jt][0] = v0; acc[jt][1] = v1; acc[jt][2] = v2; acc[jt][3] = v3;
            nsq += v0 * v0 + v1 * v1 + v2 * v2 + v3 * v3;
        }
        nsq += __shfl_xor(nsq, 16); nsq += __shfl_xor(nsq, 32);
        float inv = 1.f / fmaxf(sqrtf(nsq), EPS_COS);

        if (i < N) {
#pragma unroll
            for (int jt = 0; jt < 8; ++jt) {
                hn8[(size_t)i * 32 + jt * 4 + g] =
                    pk_fp8x4(acc[jt][0] * inv, acc[jt][1] * inv,
                             acc[jt][2] * inv, acc[jt][3] * inv);
            }
        }
    }
}

// per-bucket counting sort + fused initl->f16 convert on extra blocks
__global__ void csrfin_kernel(const unsigned* __restrict__ stage,
                              const int* __restrict__ gcur,
                              int2* __restrict__ rowpc, int* __restrict__ dstc_csr,
                              const float* __restrict__ initl,
                              _Float16* __restrict__ inith,
                              int N, int NB, int cap)
{
    const int b = blockIdx.x;
    const int t = threadIdx.x;
    if (b >= NB) {
        int idx = (b - NB) * 256 + t;
        int stride = (gridDim.x - NB) * 256;
        int M4 = N * 4;
        for (int i = idx; i < M4; i += stride) {
            float4 v = ((const float4*)initl)[i];
            h4 o;
            o[0] = (_Float16)v.x; o[1] = (_Float16)v.y;
            o[2] = (_Float16)v.z; o[3] = (_Float16)v.w;
            ((h4*)inith)[i] = o;
        }
        return;
    }

    __shared__ int cnt[256];
    __shared__ int wsum[4];
    const int lane = t & 63;
    const int lo = b << 8;
    const int base = b * cap;
    const int m = gcur[b];

    cnt[t] = 0;
    __syncthreads();
    for (int i = t; i < m; i += 256)
        atomicAdd(&cnt[(stage[base + i] >> 19) & 255], 1);
    __syncthreads();
    int c = cnt[t];
    int v = c;
#pragma unroll
    for (int mm = 1; mm <= 32; mm <<= 1) {
        int u = __shfl_up(v, mm);
        if (lane >= mm) v += u;
    }
    if (lane == 63) wsum[t >> 6] = v;
    __syncthreads();
    int woff = 0;
    for (int w = 0; w < (t >> 6); ++w) woff += wsum[w];
    int excl = woff + v - c;
    if (lo + t < N) rowpc[lo + t] = make_int2(base + excl, c);
    __syncthreads();
    cnt[t] = base + excl;
    __syncthreads();
    for (int i = t; i < m; i += 256) {
        unsigned v2 = stage[base + i];
        int pos = atomicAdd(&cnt[(v2 >> 19) & 255], 1);
        dstc_csr[pos] = (int)(v2 & 0x1FFFF) | (int)(((v2 >> 17) & 3) << 24);
    }
}

// -------- fused per-node sim (fp8 MFMA) + LAYER-1 propagation ---------------
// nt loads for streamed dstc; nt stores for wq (read much later) and out1
// (read randomly by next layer from all XCDs -> push dirty data to L3).
__global__ void node_sim_kernel(const unsigned char* __restrict__ hn8,
    const int2* __restrict__ rowpc, const int* __restrict__ dstc_csr,
    const float* __restrict__ ew0, const float* __restrict__ ew1,
    const float* __restrict__ ew2, unsigned* __restrict__ wq_csr,
    float* __restrict__ scl, const _Float16* __restrict__ inith,
    _Float16* __restrict__ out1, int N)
{
    const int gtid = blockIdx.x * blockDim.x + threadIdx.x;
    const int lane = threadIdx.x & 63;
    const int c16  = lane & 15;
    const int g    = lane >> 4;
    const int wv   = gtid >> 6;
    const int nwv  = (gridDim.x * blockDim.x) >> 6;
    const float sg0 = 1.f / (1.f + expf(-ew0[0]));
    const float sg1 = 1.f / (1.f + expf(-ew1[0]));
    const float sg2 = 1.f / (1.f + expf(-ew2[0]));
    const int srcl = ((c16 >> 2) << 4) | c16;
    const int j4   = c16 & 3;

    for (int n = wv; n < N; n += nwv) {
        const int2 pc = rowpc[n];
        const int beg = pc.x, deg = pc.y;
        const int end = beg + deg;
        if (deg == 0) {
            if (lane == 0) scl[n] = ALPHA_;
            if (c16 == 0) {
                h4 ivn = *(const h4*)&inith[(size_t)n * 16 + g * 4];
                h4 st;
#pragma unroll
                for (int k = 0; k < 4; ++k)
                    st[k] = (_Float16)((1.f - ALPHA_) * (float)ivn[k]);
                __builtin_nontemporal_store(*(const long*)&st,
                    (long*)&out1[(size_t)n * 16 + g * 4]);
            }
            continue;
        }

        const unsigned char* sp = hn8 + (size_t)n * 128 + g * 16;
        lx2 B0 = *(const lx2*)sp;
        lx2 B1 = *(const lx2*)(sp + 64);

        float total = 0.f;
        float p1[4] = {0.f, 0.f, 0.f, 0.f};
        const int nb = (deg + 15) >> 4;
        for (int kb = 0; kb < nb; ++kb) {
            const int ebase = beg + (kb << 4);
            const int rem = end - ebase;
            int vv = (c16 < rem) ? __builtin_nontemporal_load(&dstc_csr[ebase + c16]) : 0;
            int dl = (c16 < rem) ? (vv & 0x1FFFF) : n;
            const unsigned char* rp = hn8 + (size_t)dl * 128 + g * 16;
            lx2 A0 = *(const lx2*)rp;
            lx2 A1 = *(const lx2*)(rp + 64);
            h4 ivd = *(const h4*)&inith[(size_t)dl * 16 + g * 4];

            f32x4 acc = {0.f, 0.f, 0.f, 0.f};
            acc = __builtin_amdgcn_mfma_f32_16x16x32_fp8_fp8(A0[0], B0[0], acc, 0, 0, 0);
            acc = __builtin_amdgcn_mfma_f32_16x16x32_fp8_fp8(A0[1], B0[1], acc, 0, 0, 0);
            acc = __builtin_amdgcn_mfma_f32_16x16x32_fp8_fp8(A1[0], B1[0], acc, 0, 0, 0);
            acc = __builtin_amdgcn_mfma_f32_16x16x32_fp8_fp8(A1[1], B1[1], acc, 0, 0, 0);

            float a01  = (j4 & 1) ? acc[1] : acc[0];
            float a23  = (j4 & 1) ? acc[3] : acc[2];
            float asel = (j4 & 2) ? a23 : a01;
            float mysim = __shfl(asel, srcl);

            int cls = (vv >> 24) & 3;
            float sgc = (cls == 0) ? sg0 : (cls == 1) ? sg1 : sg2;
            float w = sgc * mysim;
            if (c16 < rem) {
                total += w;
#pragma unroll
                for (int k = 0; k < 4; ++k) p1[k] += w * (float)ivd[k];
            }

            if (g == 0 && c16 < rem) {
                int q = (int)(w * 16000.f + ((w >= 0.f) ? 0.5f : -0.5f)) + 16384;
                q = min(max(q, 0), 32767);
                unsigned pw = ((unsigned)vv & 0x1FFFFu) | ((unsigned)q << 17);
                __builtin_nontemporal_store(pw, &wq_csr[ebase + c16]);
            }
        }
        total += __shfl_xor(total, 1);
        total += __shfl_xor(total, 2);
        total += __shfl_xor(total, 4);
        total += __shfl_xor(total, 8);
#pragma unroll
        for (int k = 0; k < 4; ++k) {
            p1[k] += __shfl_xor(p1[k], 1);
            p1[k] += __shfl_xor(p1[k], 2);
            p1[k] += __shfl_xor(p1[k], 4);
            p1[k] += __shfl_xor(p1[k], 8);
        }
        float s = ALPHA_ * ((total > 0.f) ? 1.f / total : 1.f);
        if (lane == 0) scl[n] = s;
        if (c16 == 0) {
            h4 ivn = *(const h4*)&inith[(size_t)n * 16 + g * 4];
            h4 st;
#pragma unroll
            for (int k = 0; k < 4; ++k)
                st[k] = (_Float16)(s * p1[k] + (1.f - ALPHA_) * (float)ivn[k]);
            __builtin_nontemporal_store(*(const long*)&st,
                (long*)&out1[(size_t)n * 16 + g * 4]);
        }
    }
}

// ---------------- propagation: out = scl*sum(wraw*cur[dst]) + 0.5*init ------
// TWO nodes per wave. nt loads for streamed wq/inith (keep L2 for cur);
// nt stores for intermediate cur (push to L3 for next layer's random reads).
template<bool LAST>
__global__ void prop_kernel(const int2* __restrict__ rowpc,
    const unsigned* __restrict__ wq_csr, const float* __restrict__ scl,
    const _Float16* __restrict__ cur, const _Float16* __restrict__ inith,
    float* __restrict__ out32, _Float16* __restrict__ out16, int N)
{
    const int gtid = blockIdx.x * blockDim.x + threadIdx.x;
    const int lane = threadIdx.x & 63;
    const int half = lane >> 5;
    const int l32  = lane & 31;
    const int sg   = l32 >> 2;
    const int c4   = l32 & 3;
    const int wv   = gtid >> 6;
    const int nwv  = (gridDim.x * blockDim.x) >> 6;
    const float dq = 1.f / 16000.f;
    for (int n = 2 * wv + half; n < N; n += 2 * nwv) {
        int2 pc = rowpc[n];
        int beg = pc.x, end = pc.x + pc.y;
        float a0 = 0.f, a1 = 0.f, a2 = 0.f, a3 = 0.f;
#pragma unroll 4
        for (int e = beg + sg; e < end; e += 8) {
            unsigned u = __builtin_nontemporal_load(&wq_csr[e]);
            int d = (int)(u & 0x1FFFFu);
            float w = (float)((int)(u >> 17) - 16384) * dq;
            h4 cv = *(const h4*)&cur[(size_t)d * 16 + c4 * 4];
            a0 += w * (float)cv[0];
            a1 += w * (float)cv[1];
            a2 += w * (float)cv[2];
            a3 += w * (float)cv[3];
        }
#pragma unroll
        for (int m = 4; m <= 16; m <<= 1) {
            a0 += __shfl_xor(a0, m);
            a1 += __shfl_xor(a1, m);
            a2 += __shfl_xor(a2, m);
            a3 += __shfl_xor(a3, m);
        }
        if (sg == 0) {
            float sc = scl[n];
            long ivl = __builtin_nontemporal_load(
                (const long*)&inith[(size_t)n * 16 + c4 * 4]);
            h4 iv = *(const h4*)&ivl;
            float r0 = sc * a0 + (1.f - ALPHA_) * (float)iv[0];
            float r1 = sc * a1 + (1.f - ALPHA_) * (float)iv[1];
            float r2 = sc * a2 + (1.f - ALPHA_) * (float)iv[2];
            float r3 = sc * a3 + (1.f - ALPHA_) * (float)iv[3];
            if (LAST) {
                float4 st; st.x = r0; st.y = r1; st.z = r2; st.w = r3;
                *(float4*)&out32[(size_t)n * 16 + c4 * 4] = st;
            } else {
                h4 st;
                st[0] = (_Float16)r0; st[1] = (_Float16)r1;
                st[2] = (_Float16)r2; st[3] = (_Float16)r3;
                __builtin_nontemporal_store(*(const long*)&st,
                    (long*)&out16[(size_t)n * 16 + c4 * 4]);
            }
        }
    }
}

extern "C" void kernel_launch(void* const* d_in, const int* in_sizes, int n_in,
                              void* d_out, int out_size, void* d_ws, size_t ws_size,
                              hipStream_t stream)
{
    const float* feat  = (const float*)d_in[0];
    const float* initl = (const float*)d_in[1];
    const float* W     = (const float*)d_in[2];
    const float* b     = (const float*)d_in[3];
    const float* gam   = (const float*)d_in[4];
    const float* bet   = (const float*)d_in[5];
    const float* ew0   = (const float*)d_in[6];
    const float* ew1   = (const float*)d_in[7];
    const float* ew2   = (const float*)d_in[8];
    const int* s0  = (const int*)d_in[9];
    const int* dd0 = (const int*)d_in[10];
    const int* s1  = (const int*)d_in[11];
    const int* dd1 = (const int*)d_in[12];
    const int* s2  = (const int*)d_in[13];
    const int* dd2 = (const int*)d_in[14];

    const int N = in_sizes[0] / DD;
    const int E = in_sizes[9];
    const int totE = 3 * E;
    const int NB = (N + 255) >> 8;
    const int cap = (totE + NB - 1) / NB + 2048;
    float* out = (float*)d_out;

    char* ws = (char*)d_ws;
    size_t off = 0;
    auto alloc = [&](size_t bytes) -> void* {
        void* p = ws + off;
        off += (bytes + 255) & ~(size_t)255;
        return p;
    };
    unsigned*  hn8     = (unsigned*)alloc((size_t)N * DD);
    int*       gcur    = (int*)alloc((size_t)NB * 4);
    int2*      rowpc   = (int2*)alloc((size_t)N * 8);
    unsigned*  stage   = (unsigned*)alloc((size_t)NB * cap * 4);
    int*       dstc_csr= (int*)alloc((size_t)NB * cap * 4);
    unsigned*  wq_csr  = (unsigned*)alloc((size_t)NB * cap * 4);
    float*     scl     = (float*)alloc((size_t)N * 4);
    _Float16*  inith   = (_Float16*)alloc((size_t)N * CC * 2);
    _Float16*  curA    = (_Float16*)alloc((size_t)N * CC * 2);
    _Float16*  curB    = (_Float16*)alloc((size_t)N * CC * 2);

    // 1) fused: feature transform (MFMA) ∥ padded-bucket edge partition
    const int FTB = 512, PB = 1024;
    hipMemsetAsync(gcur, 0, (size_t)NB * 4, stream);
    ft_bpart_kernel<<<FTB + PB, 256, 0, stream>>>(
        feat, W, b, gam, bet, hn8, N,
        s0, dd0, s1, dd1, s2, dd2, gcur, stage, E, NB, cap, FTB, PB);

    // 2) csrfin (+ fused initl->f16 cvt on the extra blocks)
    csrfin_kernel<<<NB + 1024, 256, 0, stream>>>(stage, gcur, rowpc, dstc_csr,
                                                 initl, inith, N, NB, cap);

    // 3) fused edge weights + layer-1 propagation -> wq_csr, scl, curA
    const int wblk = (N * 64 + 255) / 256;
    node_sim_kernel<<<wblk, 256, 0, stream>>>((const unsigned char*)hn8,
                                              rowpc, dstc_csr,
                                              ew0, ew1, ew2, wq_csr, scl,
                                              inith, curA, N);

    // 4) layers 2-5 (ping-pong A->B->A->B->out), 2 nodes per wave
    const int pblk = (N * 32 + 255) / 256;
    const _Float16* cs = curA;
    _Float16* bufs[2] = { curB, curA };
    for (int layer = 0; layer < 3; ++layer) {
        _Float16* dst = bufs[layer & 1];
        prop_kernel<false><<<pblk, 256, 0, stream>>>(rowpc, wq_csr, scl,
                                                     cs, inith, nullptr, dst, N);
        cs = dst;
    }
    prop_kernel<true><<<pblk, 256, 0, stream>>>(rowpc, wq_csr, scl,
                                                cs, inith, out, nullptr, N);
}

// Round 19
// 321.355 us; speedup vs baseline: 1.1069x; 1.1069x over previous
//
#include <hip/hip_runtime.h>
#include <hip/hip_fp8.h>
#include <math.h>

#define DD 128
#define CC 16
#define ALPHA_ 0.5f
#define EPS_LN 1e-5f
#define EPS_COS 1e-8f

typedef _Float16 h4 __attribute__((ext_vector_type(4)));
typedef _Float16 f16x8 __attribute__((ext_vector_type(8)));
typedef float f32x4 __attribute__((ext_vector_type(4)));
typedef long lx2 __attribute__((ext_vector_type(2)));

__device__ __forceinline__ unsigned pk_fp8x4(float v0, float v1, float v2, float v3) {
#if __has_builtin(__builtin_amdgcn_cvt_pk_fp8_f32)
    int u = 0;
    u = __builtin_amdgcn_cvt_pk_fp8_f32(v0, v1, u, false);
    u = __builtin_amdgcn_cvt_pk_fp8_f32(v2, v3, u, true);
    return (unsigned)u;
#else
    __hip_fp8_e4m3 a(v0), b(v1), c(v2), d(v3);
    return (unsigned)a.__x | ((unsigned)b.__x << 8)
         | ((unsigned)c.__x << 16) | ((unsigned)d.__x << 24);
#endif
}

// ============ FAT kernel: ft (MFMA transform) ∥ bpart (bucket partition) ====
__global__ __launch_bounds__(256, 2) void ft_bpart_kernel(
    const float* __restrict__ feat, const float* __restrict__ W,
    const float* __restrict__ bias, const float* __restrict__ gamma,
    const float* __restrict__ beta, unsigned* __restrict__ hn8, int N,
    const int* __restrict__ s0, const int* __restrict__ d0,
    const int* __restrict__ s1, const int* __restrict__ d1,
    const int* __restrict__ s2, const int* __restrict__ d2,
    int* __restrict__ gcur, unsigned* __restrict__ stage,
    int E, int NB, int cap, int FTB, int PB)
{
    __shared__ int cnt[512];
    __shared__ int rbase[512];

    if ((int)blockIdx.x >= FTB) {
        // ---------------- bpart ----------------
        const int bidx = blockIdx.x - FTB;
        const int tid = threadIdx.x;
        for (int i = tid; i < NB; i += 256) cnt[i] = 0;
        __syncthreads();
        const int tot = 3 * E;
        const int chunk = (tot + PB - 1) / PB;
        const int lo = bidx * chunk, hi = min(lo + chunk, tot);
        for (int i = lo + tid; i < hi; i += 256) {
            int src = (i < E) ? s0[i] : (i < 2 * E) ? s1[i - E] : s2[i - 2 * E];
            atomicAdd(&cnt[src >> 8], 1);
        }
        __syncthreads();
        for (int i = tid; i < NB; i += 256) {
            int c = cnt[i];
            rbase[i] = c ? (i * cap + atomicAdd(&gcur[i], c)) : 0;
            cnt[i] = 0;
        }
        __syncthreads();
        for (int i = lo + tid; i < hi; i += 256) {
            int src, dst, cls;
            if (i < E)          { src = s0[i];         dst = d0[i];         cls = 0; }
            else if (i < 2 * E) { src = s1[i - E];     dst = d1[i - E];     cls = 1; }
            else                { src = s2[i - 2 * E]; dst = d2[i - 2 * E]; cls = 2; }
            int b = src >> 8;
            int pos = rbase[b] + atomicAdd(&cnt[b], 1);
            stage[pos] = (unsigned)dst | ((unsigned)cls << 17)
                       | ((unsigned)(src & 255) << 19);
        }
        return;
    }

    // ---------------- ft (MFMA) ----------------
    const int lane = threadIdx.x & 63;
    const int c16  = lane & 15;
    const int g    = lane >> 4;
    const int wv   = ((int)blockIdx.x * 256 + (int)threadIdx.x) >> 6;
    const int nwv  = (FTB * 256) >> 6;

    f16x8 wf[8][4];
#pragma unroll
    for (int jt = 0; jt < 8; ++jt) {
        const float* wr = W + (size_t)(jt * 16 + c16) * 128 + g * 8;
#pragma unroll
        for (int s = 0; s < 4; ++s) {
            float4 lo = *(const float4*)(wr + s * 32);
            float4 hi = *(const float4*)(wr + s * 32 + 4);
            f16x8 f;
            f[0] = (_Float16)lo.x; f[1] = (_Float16)lo.y;
            f[2] = (_Float16)lo.z; f[3] = (_Float16)lo.w;
            f[4] = (_Float16)hi.x; f[5] = (_Float16)hi.y;
            f[6] = (_Float16)hi.z; f[7] = (_Float16)hi.w;
            wf[jt][s] = f;
        }
    }

    const int ntiles = (N + 15) >> 4;
    for (int t = wv; t < ntiles; t += nwv) {
        const int i = (t << 4) + c16;
        const float* fr = feat + (size_t)min(i, N - 1) * 128 + g * 8;
        f16x8 bf[4];
#pragma unroll
        for (int s = 0; s < 4; ++s) {
            float4 lo = *(const float4*)(fr + s * 32);
            float4 hi = *(const float4*)(fr + s * 32 + 4);
            f16x8 f;
            f[0] = (_Float16)lo.x; f[1] = (_Float16)lo.y;
            f[2] = (_Float16)lo.z; f[3] = (_Float16)lo.w;
            f[4] = (_Float16)hi.x; f[5] = (_Float16)hi.y;
            f[6] = (_Float16)hi.z; f[7] = (_Float16)hi.w;
            bf[s] = f;
        }

        f32x4 acc[8] = {};
#pragma unroll
        for (int s = 0; s < 4; ++s)
#pragma unroll
            for (int jt = 0; jt < 8; ++jt)
                acc[jt] = __builtin_amdgcn_mfma_f32_16x16x32_f16(
                    wf[jt][s], bf[s], acc[jt], 0, 0, 0);

        float s1 = 0.f, s2 = 0.f;
#pragma unroll
        for (int jt = 0; jt < 8; ++jt) {
            float4 bb = ((const float4*)bias)[jt * 4 + g];
            float h0 = acc[jt][0] + bb.x, h1 = acc[jt][1] + bb.y;
            float h2_ = acc[jt][2] + bb.z, h3 = acc[jt][3] + bb.w;
            acc[jt][0] = h0; acc[jt][1] = h1; acc[jt][2] = h2_; acc[jt][3] = h3;
            s1 += h0 + h1 + h2_ + h3;
            s2 += h0 * h0 + h1 * h1 + h2_ * h2_ + h3 * h3;
        }
        s1 += __shfl_xor(s1, 16); s1 += __shfl_xor(s1, 32);
        s2 += __shfl_xor(s2, 16); s2 += __shfl_xor(s2, 32);
        float mu   = s1 * (1.f / 128.f);
        float var  = s2 * (1.f / 128.f) - mu * mu;
        float rstd = rsqrtf(var + EPS_LN);

        float nsq = 0.f;
#pragma unroll
        for (int jt = 0; jt < 8; ++jt) {
            float4 gg = ((const float4*)gamma)[jt * 4 + g];
            float4 be = ((const float4*)beta)[jt * 4 + g];
            float v0 = fmaxf((acc[jt][0] - mu) * rstd * gg.x + be.x, 0.f);
            float v1 = fmaxf((acc[jt][1] - mu) * rstd * gg.y + be.y, 0.f);
            float v2 = fmaxf((acc[jt][2] - mu) * rstd * gg.z + be.z, 0.f);
            float v3 = fmaxf((acc[jt][3] - mu) * rstd * gg.w + be.w, 0.f);
            acc[jt][0] = v0; acc[jt][1] = v1; acc[jt][2] = v2; acc[jt][3] = v3;
            nsq += v0 * v0 + v1 * v1 + v2 * v2 + v3 * v3;
        }
        nsq += __shfl_xor(nsq, 16); nsq += __shfl_xor(nsq, 32);
        float inv = 1.f / fmaxf(sqrtf(nsq), EPS_COS);

        if (i < N) {
#pragma unroll
            for (int jt = 0; jt < 8; ++jt) {
                hn8[(size_t)i * 32 + jt * 4 + g] =
                    pk_fp8x4(acc[jt][0] * inv, acc[jt][1] * inv,
                             acc[jt][2] * inv, acc[jt][3] * inv);
            }
        }
    }
}

// per-bucket counting sort + fused initl->f16 convert on extra blocks
__global__ void csrfin_kernel(const unsigned* __restrict__ stage,
                              const int* __restrict__ gcur,
                              int2* __restrict__ rowpc, int* __restrict__ dstc_csr,
                              const float* __restrict__ initl,
                              _Float16* __restrict__ inith,
                              int N, int NB, int cap)
{
    const int b = blockIdx.x;
    const int t = threadIdx.x;
    if (b >= NB) {
        int idx = (b - NB) * 256 + t;
        int stride = (gridDim.x - NB) * 256;
        int M4 = N * 4;
        for (int i = idx; i < M4; i += stride) {
            float4 v = ((const float4*)initl)[i];
            h4 o;
            o[0] = (_Float16)v.x; o[1] = (_Float16)v.y;
            o[2] = (_Float16)v.z; o[3] = (_Float16)v.w;
            ((h4*)inith)[i] = o;
        }
        return;
    }

    __shared__ int cnt[256];
    __shared__ int wsum[4];
    const int lane = t & 63;
    const int lo = b << 8;
    const int base = b * cap;
    const int m = gcur[b];

    cnt[t] = 0;
    __syncthreads();
    for (int i = t; i < m; i += 256)
        atomicAdd(&cnt[(stage[base + i] >> 19) & 255], 1);
    __syncthreads();
    int c = cnt[t];
    int v = c;
#pragma unroll
    for (int mm = 1; mm <= 32; mm <<= 1) {
        int u = __shfl_up(v, mm);
        if (lane >= mm) v += u;
    }
    if (lane == 63) wsum[t >> 6] = v;
    __syncthreads();
    int woff = 0;
    for (int w = 0; w < (t >> 6); ++w) woff += wsum[w];
    int excl = woff + v - c;
    if (lo + t < N) rowpc[lo + t] = make_int2(base + excl, c);
    __syncthreads();
    cnt[t] = base + excl;
    __syncthreads();
    for (int i = t; i < m; i += 256) {
        unsigned v2 = stage[base + i];
        int pos = atomicAdd(&cnt[(v2 >> 19) & 255], 1);
        dstc_csr[pos] = (int)(v2 & 0x1FFFF) | (int)(((v2 >> 17) & 3) << 24);
    }
}

// -------- fused per-node sim (fp8 MFMA) + LAYER-1 propagation ---------------
__global__ void node_sim_kernel(const unsigned char* __restrict__ hn8,
    const int2* __restrict__ rowpc, const int* __restrict__ dstc_csr,
    const float* __restrict__ ew0, const float* __restrict__ ew1,
    const float* __restrict__ ew2, unsigned* __restrict__ wq_csr,
    float* __restrict__ scl, const _Float16* __restrict__ inith,
    _Float16* __restrict__ out1, int N)
{
    const int gtid = blockIdx.x * blockDim.x + threadIdx.x;
    const int lane = threadIdx.x & 63;
    const int c16  = lane & 15;
    const int g    = lane >> 4;
    const int wv   = gtid >> 6;
    const int nwv  = (gridDim.x * blockDim.x) >> 6;
    const float sg0 = 1.f / (1.f + expf(-ew0[0]));
    const float sg1 = 1.f / (1.f + expf(-ew1[0]));
    const float sg2 = 1.f / (1.f + expf(-ew2[0]));
    const int srcl = ((c16 >> 2) << 4) | c16;
    const int j4   = c16 & 3;

    for (int n = wv; n < N; n += nwv) {
        const int2 pc = rowpc[n];
        const int beg = pc.x, deg = pc.y;
        const int end = beg + deg;
        if (deg == 0) {
            if (lane == 0) scl[n] = ALPHA_;
            if (c16 == 0) {
                h4 ivn = *(const h4*)&inith[(size_t)n * 16 + g * 4];
                h4 st;
#pragma unroll
                for (int k = 0; k < 4; ++k)
                    st[k] = (_Float16)((1.f - ALPHA_) * (float)ivn[k]);
                *(h4*)&out1[(size_t)n * 16 + g * 4] = st;
            }
            continue;
        }

        const unsigned char* sp = hn8 + (size_t)n * 128 + g * 16;
        lx2 B0 = *(const lx2*)sp;
        lx2 B1 = *(const lx2*)(sp + 64);

        float total = 0.f;
        float p1[4] = {0.f, 0.f, 0.f, 0.f};
        const int nb = (deg + 15) >> 4;
        for (int kb = 0; kb < nb; ++kb) {
            const int ebase = beg + (kb << 4);
            const int rem = end - ebase;
            int vv = (c16 < rem) ? dstc_csr[ebase + c16] : 0;
            int dl = (c16 < rem) ? (vv & 0x1FFFF) : n;
            const unsigned char* rp = hn8 + (size_t)dl * 128 + g * 16;
            lx2 A0 = *(const lx2*)rp;
            lx2 A1 = *(const lx2*)(rp + 64);
            h4 ivd = *(const h4*)&inith[(size_t)dl * 16 + g * 4];

            f32x4 acc = {0.f, 0.f, 0.f, 0.f};
            acc = __builtin_amdgcn_mfma_f32_16x16x32_fp8_fp8(A0[0], B0[0], acc, 0, 0, 0);
            acc = __builtin_amdgcn_mfma_f32_16x16x32_fp8_fp8(A0[1], B0[1], acc, 0, 0, 0);
            acc = __builtin_amdgcn_mfma_f32_16x16x32_fp8_fp8(A1[0], B1[0], acc, 0, 0, 0);
            acc = __builtin_amdgcn_mfma_f32_16x16x32_fp8_fp8(A1[1], B1[1], acc, 0, 0, 0);

            float a01  = (j4 & 1) ? acc[1] : acc[0];
            float a23  = (j4 & 1) ? acc[3] : acc[2];
            float asel = (j4 & 2) ? a23 : a01;
            float mysim = __shfl(asel, srcl);

            int cls = (vv >> 24) & 3;
            float sgc = (cls == 0) ? sg0 : (cls == 1) ? sg1 : sg2;
            float w = sgc * mysim;
            if (c16 < rem) {
                total += w;
#pragma unroll
                for (int k = 0; k < 4; ++k) p1[k] += w * (float)ivd[k];
            }

            if (g == 0 && c16 < rem) {
                int q = (int)(w * 16000.f + ((w >= 0.f) ? 0.5f : -0.5f)) + 16384;
                q = min(max(q, 0), 32767);
                wq_csr[ebase + c16] = ((unsigned)vv & 0x1FFFFu)
                                    | ((unsigned)q << 17);
            }
        }
        total += __shfl_xor(total, 1);
        total += __shfl_xor(total, 2);
        total += __shfl_xor(total, 4);
        total += __shfl_xor(total, 8);
#pragma unroll
        for (int k = 0; k < 4; ++k) {
            p1[k] += __shfl_xor(p1[k], 1);
            p1[k] += __shfl_xor(p1[k], 2);
            p1[k] += __shfl_xor(p1[k], 4);
            p1[k] += __shfl_xor(p1[k], 8);
        }
        float s = ALPHA_ * ((total > 0.f) ? 1.f / total : 1.f);
        if (lane == 0) scl[n] = s;
        if (c16 == 0) {
            h4 ivn = *(const h4*)&inith[(size_t)n * 16 + g * 4];
            h4 st;
#pragma unroll
            for (int k = 0; k < 4; ++k)
                st[k] = (_Float16)(s * p1[k] + (1.f - ALPHA_) * (float)ivn[k]);
            *(h4*)&out1[(size_t)n * 16 + g * 4] = st;
        }
    }
}

// ---------------- propagation: out = scl*sum(wraw*cur[dst]) + 0.5*init ------
// TWO nodes per wave (32 lanes each): 8 edge-subgroups x 4 class-lanes.
template<bool LAST>
__global__ void prop_kernel(const int2* __restrict__ rowpc,
    const unsigned* __restrict__ wq_csr, const float* __restrict__ scl,
    const _Float16* __restrict__ cur, const _Float16* __restrict__ inith,
    float* __restrict__ out32, _Float16* __restrict__ out16, int N)
{
    const int gtid = blockIdx.x * blockDim.x + threadIdx.x;
    const int lane = threadIdx.x & 63;
    const int half = lane >> 5;
    const int l32  = lane & 31;
    const int sg   = l32 >> 2;
    const int c4   = l32 & 3;
    const int wv   = gtid >> 6;
    const int nwv  = (gridDim.x * blockDim.x) >> 6;
    const float dq = 1.f / 16000.f;
    for (int n = 2 * wv + half; n < N; n += 2 * nwv) {
        int2 pc = rowpc[n];
        int beg = pc.x, end = pc.x + pc.y;
        float a0 = 0.f, a1 = 0.f, a2 = 0.f, a3 = 0.f;
#pragma unroll 4
        for (int e = beg + sg; e < end; e += 8) {
            unsigned u = wq_csr[e];
            int d = (int)(u & 0x1FFFFu);
            float w = (float)((int)(u >> 17) - 16384) * dq;
            h4 cv = *(const h4*)&cur[(size_t)d * 16 + c4 * 4];
            a0 += w * (float)cv[0];
            a1 += w * (float)cv[1];
            a2 += w * (float)cv[2];
            a3 += w * (float)cv[3];
        }
#pragma unroll
        for (int m = 4; m <= 16; m <<= 1) {
            a0 += __shfl_xor(a0, m);
            a1 += __shfl_xor(a1, m);
            a2 += __shfl_xor(a2, m);
            a3 += __shfl_xor(a3, m);
        }
        if (sg == 0) {
            float sc = scl[n];
            h4 iv = *(const h4*)&inith[(size_t)n * 16 + c4 * 4];
            float r0 = sc * a0 + (1.f - ALPHA_) * (float)iv[0];
            float r1 = sc * a1 + (1.f - ALPHA_) * (float)iv[1];
            float r2 = sc * a2 + (1.f - ALPHA_) * (float)iv[2];
            float r3 = sc * a3 + (1.f - ALPHA_) * (float)iv[3];
            if (LAST) {
                float4 st; st.x = r0; st.y = r1; st.z = r2; st.w = r3;
                *(float4*)&out32[(size_t)n * 16 + c4 * 4] = st;
            } else {
                h4 st;
                st[0] = (_Float16)r0; st[1] = (_Float16)r1;
                st[2] = (_Float16)r2; st[3] = (_Float16)r3;
                *(h4*)&out16[(size_t)n * 16 + c4 * 4] = st;
            }
        }
    }
}

extern "C" void kernel_launch(void* const* d_in, const int* in_sizes, int n_in,
                              void* d_out, int out_size, void* d_ws, size_t ws_size,
                              hipStream_t stream)
{
    const float* feat  = (const float*)d_in[0];
    const float* initl = (const float*)d_in[1];
    const float* W     = (const float*)d_in[2];
    const float* b     = (const float*)d_in[3];
    const float* gam   = (const float*)d_in[4];
    const float* bet   = (const float*)d_in[5];
    const float* ew0   = (const float*)d_in[6];
    const float* ew1   = (const float*)d_in[7];
    const float* ew2   = (const float*)d_in[8];
    const int* s0  = (const int*)d_in[9];
    const int* dd0 = (const int*)d_in[10];
    const int* s1  = (const int*)d_in[11];
    const int* dd1 = (const int*)d_in[12];
    const int* s2  = (const int*)d_in[13];
    const int* dd2 = (const int*)d_in[14];

    const int N = in_sizes[0] / DD;
    const int E = in_sizes[9];
    const int totE = 3 * E;
    const int NB = (N + 255) >> 8;
    const int cap = (totE + NB - 1) / NB + 2048;
    float* out = (float*)d_out;

    char* ws = (char*)d_ws;
    size_t off = 0;
    auto alloc = [&](size_t bytes) -> void* {
        void* p = ws + off;
        off += (bytes + 255) & ~(size_t)255;
        return p;
    };
    unsigned*  hn8     = (unsigned*)alloc((size_t)N * DD);
    int*       gcur    = (int*)alloc((size_t)NB * 4);
    int2*      rowpc   = (int2*)alloc((size_t)N * 8);
    unsigned*  stage   = (unsigned*)alloc((size_t)NB * cap * 4);
    int*       dstc_csr= (int*)alloc((size_t)NB * cap * 4);
    unsigned*  wq_csr  = (unsigned*)alloc((size_t)NB * cap * 4);
    float*     scl     = (float*)alloc((size_t)N * 4);
    _Float16*  inith   = (_Float16*)alloc((size_t)N * CC * 2);
    _Float16*  curA    = (_Float16*)alloc((size_t)N * CC * 2);
    _Float16*  curB    = (_Float16*)alloc((size_t)N * CC * 2);

    // 1) fused: feature transform (MFMA) ∥ padded-bucket edge partition
    const int FTB = 512, PB = 1024;
    hipMemsetAsync(gcur, 0, (size_t)NB * 4, stream);
    ft_bpart_kernel<<<FTB + PB, 256, 0, stream>>>(
        feat, W, b, gam, bet, hn8, N,
        s0, dd0, s1, dd1, s2, dd2, gcur, stage, E, NB, cap, FTB, PB);

    // 2) csrfin (+ fused initl->f16 cvt on the extra blocks)
    csrfin_kernel<<<NB + 1024, 256, 0, stream>>>(stage, gcur, rowpc, dstc_csr,
                                                 initl, inith, N, NB, cap);

    // 3) fused edge weights + layer-1 propagation -> wq_csr, scl, curA
    const int wblk = (N * 64 + 255) / 256;
    node_sim_kernel<<<wblk, 256, 0, stream>>>((const unsigned char*)hn8,
                                              rowpc, dstc_csr,
                                              ew0, ew1, ew2, wq_csr, scl,
                                              inith, curA, N);

    // 4) layers 2-5 (ping-pong A->B->A->B->out), 2 nodes per wave
    const int pblk = (N * 32 + 255) / 256;
    const _Float16* cs = curA;
    _Float16* bufs[2] = { curB, curA };
    for (int layer = 0; layer < 3; ++layer) {
        _Float16* dst = bufs[layer & 1];
        prop_kernel<false><<<pblk, 256, 0, stream>>>(rowpc, wq_csr, scl,
                                                     cs, inith, nullptr, dst, N);
        cs = dst;
    }
    prop_kernel<true><<<pblk, 256, 0, stream>>>(rowpc, wq_csr, scl,
                                                cs, inith, out, nullptr, N);
}